// Round 7
// baseline (219.245 us; speedup 1.0000x reference)
//
#include <hip/hip_runtime.h>
#include <math.h>

#define N_NODES   15000
#define N_EDGES   60000
#define EVOCAB    54
#define NODE_INDIM 64
#define EDGE_INDIM 32
#define H  32
#define EH 64
#define N_BOND 4

#define NPB   8          // nodes per block-of-256 (8 groups of 32 lanes)
#define NBLK  (N_NODES / NPB)            // 1875
#define CAPN  48         // per-NODE edge capacity (deg ~ Poisson(4); P[>=48] ~ 0)

// ---- setup task layout (segment bases 64-aligned so shfl groups never straddle) ----
#define TASK_VOCAB (EVOCAB * 1024)                 // 55296
#define TASK_PROJ  (N_NODES * H)                   // 480000
#define TASK_EDGE_BASE (TASK_VOCAB + TASK_PROJ)    // 535296 (64-aligned)
#define TA_TOTAL   (TASK_EDGE_BASE + N_EDGES)      // 595296

// ---- workspace offsets (bytes) ----
#define WT_OFF   0          // 221184  vocab weight table [54][1024]
#define H0_OFF   221184     // 1920000
#define H1_OFF   2141184    // 1920000
#define W4_OFF   4061184    // 16384   GRU packed float4
#define W2_OFF   4077568    // 8192    GRU packed float2
#define LS0_OFF  4085760    // 60000   per-node src-logit (pairs h0)
#define BS0_OFF  4145760    // 60000   per-node dst-logit (pairs h0)
#define LS1_OFF  4205760    // 60000
#define BS1_OFF  4265760    // 60000
#define CNT_OFF  4325760    // 60000   per-NODE degree counters (zeroed by pre)
#define EPK_OFF  4385760    // 2880000 per-node packed edges [15000][48]
#define W2T1_OFF 7265760    // 262144  e1_W2 transposed [64][1024]
#define W2T2_OFF 7527904    // 262144  e2_W2 transposed [64][1024]
#define PT_OFF   7790048    // 8192    proj_W transposed [64][32]

// ===========================================================================
// K0 pre: weight transposes (coalesced via LDS tiles) + GRU pack + cnt zero.
//  blocks 0-31 : W2 transpose tiles (16 per table), [1024][64] -> [64][1024]
//  block  32   : proj_W transpose [32][64] -> PT[j*32+o]
//  blocks 33-36: GRU weight pack
//  blocks 37-95: zero cnt[15000]
// ===========================================================================
__global__ __launch_bounds__(256)
void pre_kernel(const float* __restrict__ e1_W2, const float* __restrict__ e2_W2,
                const float* __restrict__ proj_W,
                const float* __restrict__ gWih, const float* __restrict__ gWhh,
                float* __restrict__ W2T1, float* __restrict__ W2T2,
                float* __restrict__ PT,
                float4* __restrict__ Wpk4, float2* __restrict__ Wpk2,
                int* __restrict__ cnt)
{
    int b = blockIdx.x, tid = threadIdx.x;
    if (b < 32) {
        __shared__ float st[64][65];                 // +1 pad: conflict-free both phases
        const float* in = (b < 16) ? e1_W2 : e2_W2;
        float* out      = (b < 16) ? W2T1  : W2T2;
        int f0 = (b & 15) * 64;
        #pragma unroll
        for (int it = 0; it < 16; ++it) {
            int idx = it * 256 + tid;                // 0..4095
            int r = idx >> 6, c = idx & 63;
            st[r][c] = in[(f0 + r) * 64 + c];        // read coalesced
        }
        __syncthreads();
        #pragma unroll
        for (int it = 0; it < 16; ++it) {
            int idx = it * 256 + tid;
            int k = idx >> 6, f = idx & 63;
            out[k * 1024 + f0 + f] = st[f][k];       // write coalesced
        }
    } else if (b == 32) {
        __shared__ float sp2[64][33];
        #pragma unroll
        for (int it = 0; it < 8; ++it) {
            int idx = it * 256 + tid;                // 0..2047
            int o = idx >> 6, j = idx & 63;
            sp2[j][o] = proj_W[idx];                 // read coalesced
        }
        __syncthreads();
        #pragma unroll
        for (int it = 0; it < 8; ++it) {
            int idx = it * 256 + tid;
            int j = idx >> 5, o = idx & 31;
            PT[idx] = sp2[j][o];                     // write coalesced
        }
    } else if (b <= 36) {
        int q = (b - 33) * 256 + tid;                // q = j*32 + o < 1024
        int j = q >> 5, o = q & 31;
        Wpk4[q] = make_float4(gWih[o * 32 + j], gWih[(32 + o) * 32 + j],
                              gWih[(64 + o) * 32 + j], gWhh[o * 32 + j]);
        Wpk2[q] = make_float2(gWhh[(32 + o) * 32 + j], gWhh[(64 + o) * 32 + j]);
    } else {
        int idx = (b - 37) * 256 + tid;              // 59 blocks cover 15000
        if (idx < N_NODES) cnt[idx] = 0;
    }
}

// ===========================================================================
// K1 setup: vocab Wt (coalesced via W2T) | h0 projection (coalesced via PT,
//           +ls0/bs0 attention scalars) | per-NODE edge bucketing.
// Edge pack: src(14b) | vid(6b)<<14, bucket = dst node.
// ===========================================================================
__global__ __launch_bounds__(256)
void setup_kernel(const int* __restrict__ node_ids, const int* __restrict__ src,
                  const int* __restrict__ dst, const int* __restrict__ eid,
                  const float* __restrict__ node_table, const float* __restrict__ edge_table,
                  const float* __restrict__ PT, const float* __restrict__ proj_b,
                  const float* __restrict__ attn_w,
                  const float* __restrict__ e1_W1, const float* __restrict__ e1_b1,
                  const float* __restrict__ e1_b2,
                  const float* __restrict__ e2_W1, const float* __restrict__ e2_b1,
                  const float* __restrict__ e2_b2,
                  const float* __restrict__ W2T1, const float* __restrict__ W2T2,
                  float* __restrict__ Wt, float* __restrict__ h0,
                  float* __restrict__ ls, float* __restrict__ bs,
                  int* __restrict__ cnt, int* __restrict__ blkE)
{
    int t = blockIdx.x * 256 + threadIdx.x;
    if (t >= TA_TOTAL) return;
    if (t < TASK_VOCAB) {
        int v = t >> 10, f = t & 1023, l = t & 63;       // v wave-uniform
        const float* W1  = (v < N_BOND) ? e1_W1 : e2_W1;
        const float* b1  = (v < N_BOND) ? e1_b1 : e2_b1;
        const float* b2  = (v < N_BOND) ? e1_b2 : e2_b2;
        const float* W2T = (v < N_BOND) ? W2T1  : W2T2;
        const float4* ef4 = (const float4*)(edge_table + v * EDGE_INDIM);
        const float4* w14 = (const float4*)(W1 + l * EDGE_INDIM);
        float z = b1[l];
        #pragma unroll
        for (int j = 0; j < 8; ++j) {
            float4 a = ef4[j], b = w14[j];
            z += a.x*b.x + a.y*b.y + a.z*b.z + a.w*b.w;
        }
        z = fmaxf(z, 0.f);
        float y = b2[f];
        #pragma unroll 16
        for (int k = 0; k < 64; ++k)                     // coalesced 256B per k
            y += __shfl(z, k, 64) * W2T[k * 1024 + f];
        Wt[(v << 10) + f] = y;                           // [v][i*32+o]
    } else if (t < TASK_EDGE_BASE) {
        int q = t - TASK_VOCAB;
        int n = q >> 5, o = q & 31;
        int gid = node_ids[n];
        const float* nf = node_table + (size_t)gid * NODE_INDIM;
        float nfa = nf[o], nfb = nf[32 + o];             // 2 coalesced row reads
        float acc = proj_b[o];
        #pragma unroll 8
        for (int j = 0; j < 32; ++j)                     // PT: 128B coalesced, L1-hot
            acc += __shfl(nfa, j, 32) * PT[j * 32 + o];
        #pragma unroll 8
        for (int j = 0; j < 32; ++j)
            acc += __shfl(nfb, j, 32) * PT[(32 + j) * 32 + o];
        float hval = fmaxf(acc, 0.f);
        h0[q] = hval;
        float c1 = hval * attn_w[o], c2 = hval * attn_w[32 + o];
        #pragma unroll
        for (int k = 16; k > 0; k >>= 1) {
            c1 += __shfl_xor(c1, k, 32);
            c2 += __shfl_xor(c2, k, 32);
        }
        if (o == 0) { ls[n] = c1; bs[n] = c2; }
    } else {
        int e = t - TASK_EDGE_BASE;
        int d = dst[e];
        int pack = src[e] | (eid[e] << 14);              // src<2^14, vid<54
        int slot = atomicAdd(&cnt[d], 1);
        if (slot < CAPN) blkE[d * CAPN + slot] = pack;   // never overflows for this graph
    }
}

// ===========================================================================
// K2-4 mp: one kernel per step. Each 32-lane group owns ONE dst node and its
// per-node edge row: preload packed edges coalesced into lanes, shfl each
// edge out, 2-deep edge pipeline (logit from ls/bs tables + 32x32 matvec,
// scalar-column coalesced W reads), accumulate acc/sex in REGISTERS.
// Zero LDS, zero __syncthreads, no atomics: waves retire independently.
// Then softmax-normalize + relu + GRU + next-step ls/bs.
// ===========================================================================
__global__ __launch_bounds__(256)
void mp_kernel(const int* __restrict__ cnt, const int* __restrict__ blkE,
               const float* __restrict__ hc, const float* __restrict__ Wt,
               const float* __restrict__ attn_w,
               const float4* __restrict__ Wpk4, const float2* __restrict__ Wpk2,
               const float* __restrict__ gbih, const float* __restrict__ gbhh,
               const float* __restrict__ lsc, const float* __restrict__ bsc,
               float* __restrict__ lsn, float* __restrict__ bsn,
               float* __restrict__ op, int last)
{
    int b = blockIdx.x, tid = threadIdx.x;
    int g = tid >> 5, o = tid & 31;                      // 8 groups of 32 lanes
    int n = (b << 3) + g;                                // this group's node

    int deg = cnt[n];
    if (deg > CAPN) deg = CAPN;
    int pks = blkE[n * CAPN + o];                        // coalesced row preload
    float hv  = hc[(n << 5) + o];                        // coalesced
    float bdn = bsc[n];                                  // dst half of logit

    float sex = 0.f, acc = 0.f;
    int s = 0;
    for (; s + 1 < deg; s += 2) {                        // 2 edges in flight
        int pk0 = __shfl(pks, s, 32);
        int pk1 = __shfl(pks, s + 1, 32);
        int sp0 = pk0 & 0x3FFF, v0 = pk0 >> 14;
        int sp1 = pk1 & 0x3FFF, v1 = pk1 >> 14;
        float a0 = lsc[sp0] + bdn; a0 = (a0 > 0.f) ? a0 : 0.01f * a0;
        float a1 = lsc[sp1] + bdn; a1 = (a1 > 0.f) ? a1 : 0.01f * a1;
        float ex0 = __expf(a0), ex1 = __expf(a1);
        float hs0 = hc[(sp0 << 5) + o];
        float hs1 = hc[(sp1 << 5) + o];
        const float* W0 = Wt + (v0 << 10) + o;           // column o, 128B coalesced rows
        const float* W1c = Wt + (v1 << 10) + o;
        float y0 = 0.f, y1 = 0.f;
        #pragma unroll
        for (int i = 0; i < 32; ++i) {
            y0 += __shfl(hs0, i, 32) * W0[i * 32];
            y1 += __shfl(hs1, i, 32) * W1c[i * 32];
        }
        acc += ex0 * y0 + ex1 * y1;
        sex += ex0 + ex1;
    }
    if (s < deg) {                                       // odd tail
        int pk0 = __shfl(pks, s, 32);
        int sp0 = pk0 & 0x3FFF, v0 = pk0 >> 14;
        float a0 = lsc[sp0] + bdn; a0 = (a0 > 0.f) ? a0 : 0.01f * a0;
        float ex0 = __expf(a0);
        float hs0 = hc[(sp0 << 5) + o];
        const float* W0 = Wt + (v0 << 10) + o;
        float y0 = 0.f;
        #pragma unroll
        for (int i = 0; i < 32; ++i)
            y0 += __shfl(hs0, i, 32) * W0[i * 32];
        acc += ex0 * y0;
        sex += ex0;
    }
    float m = (deg > 0) ? fmaxf(acc / sex, 0.f) : 0.f;

    // GRU cell (packed-transposed weights, L1-hot broadcast reads)
    float gir = 0.f, giz = 0.f, gin = 0.f, ghr = 0.f, ghz = 0.f, ghn = 0.f;
    #pragma unroll 4
    for (int j = 0; j < 32; ++j) {
        float mj = __shfl(m, j, 32);
        float hj = __shfl(hv, j, 32);
        float4 a4 = Wpk4[j * 32 + o];
        float2 b2 = Wpk2[j * 32 + o];
        gir += mj * a4.x;  giz += mj * a4.y;  gin += mj * a4.z;
        ghr += hj * a4.w;  ghz += hj * b2.x;  ghn += hj * b2.y;
    }
    float r  = 1.f / (1.f + __expf(-(gir + gbih[o]      + ghr + gbhh[o])));
    float z  = 1.f / (1.f + __expf(-(giz + gbih[32 + o] + ghz + gbhh[32 + o])));
    float nn = tanhf(gin + gbih[64 + o] + r * (ghn + gbhh[64 + o]));
    float hid = (1.f - z) * nn + z * hv;
    op[(n << 5) + o] = hid;

    if (!last) {                                         // next step's attention scalars
        float c1 = hid * attn_w[o], c2 = hid * attn_w[32 + o];
        #pragma unroll
        for (int k = 16; k > 0; k >>= 1) {
            c1 += __shfl_xor(c1, k, 32);
            c2 += __shfl_xor(c2, k, 32);
        }
        if (o == 0) { lsn[n] = c1; bsn[n] = c2; }
    }
}

// ===========================================================================
extern "C" void kernel_launch(void* const* d_in, const int* in_sizes, int n_in,
                              void* d_out, int out_size, void* d_ws, size_t ws_size,
                              hipStream_t stream) {
    const int*   node_ids   = (const int*)d_in[0];
    const int*   edge_ids   = (const int*)d_in[1];
    const int*   srcp       = (const int*)d_in[2];
    const int*   dstp       = (const int*)d_in[3];
    const float* node_table = (const float*)d_in[4];
    const float* edge_table = (const float*)d_in[5];
    const float* proj_W     = (const float*)d_in[6];
    const float* proj_b     = (const float*)d_in[7];
    const float* attn_w     = (const float*)d_in[8];
    const float* e1_W1 = (const float*)d_in[9];  const float* e1_b1 = (const float*)d_in[10];
    const float* e1_W2 = (const float*)d_in[11]; const float* e1_b2 = (const float*)d_in[12];
    const float* e2_W1 = (const float*)d_in[13]; const float* e2_b1 = (const float*)d_in[14];
    const float* e2_W2 = (const float*)d_in[15]; const float* e2_b2 = (const float*)d_in[16];
    const float* gWih  = (const float*)d_in[17]; const float* gWhh  = (const float*)d_in[18];
    const float* gbih  = (const float*)d_in[19]; const float* gbhh  = (const float*)d_in[20];
    float* outp = (float*)d_out;

    char* ws = (char*)d_ws;
    float*  Wt   = (float*)(ws + WT_OFF);
    float*  h0b  = (float*)(ws + H0_OFF);
    float*  h1b  = (float*)(ws + H1_OFF);
    float4* Wpk4 = (float4*)(ws + W4_OFF);
    float2* Wpk2 = (float2*)(ws + W2_OFF);
    float*  ls0  = (float*)(ws + LS0_OFF);
    float*  bs0  = (float*)(ws + BS0_OFF);
    float*  ls1  = (float*)(ws + LS1_OFF);
    float*  bs1  = (float*)(ws + BS1_OFF);
    int*    cnt  = (int*)  (ws + CNT_OFF);
    int*    blkE = (int*)  (ws + EPK_OFF);
    float*  W2T1 = (float*)(ws + W2T1_OFF);
    float*  W2T2 = (float*)(ws + W2T2_OFF);
    float*  PT   = (float*)(ws + PT_OFF);

    // K0: transposes + GRU pack + cnt zero (96 blocks)
    pre_kernel<<<96, 256, 0, stream>>>(
        e1_W2, e2_W2, proj_W, gWih, gWhh, W2T1, W2T2, PT, Wpk4, Wpk2, cnt);

    setup_kernel<<<(TA_TOTAL + 255) / 256, 256, 0, stream>>>(
        node_ids, srcp, dstp, edge_ids, node_table, edge_table, PT, proj_b,
        attn_w, e1_W1, e1_b1, e1_b2, e2_W1, e2_b1, e2_b2, W2T1, W2T2,
        Wt, h0b, ls0, bs0, cnt, blkE);

    float* hc = h0b;  float* hn = h1b;
    float* lc = ls0;  float* bc = bs0;
    float* ln = ls1;  float* bn = bs1;
    for (int step = 0; step < 3; ++step) {
        int last = (step == 2);
        float* op = last ? outp : hn;
        mp_kernel<<<NBLK, 256, 0, stream>>>(
            cnt, blkE, hc, Wt, attn_w, Wpk4, Wpk2, gbih, gbhh,
            lc, bc, ln, bn, op, last);
        float* tf;
        tf = hc; hc = hn; hn = tf;
        tf = lc; lc = ln; ln = tf;
        tf = bc; bc = bn; bn = tf;
    }
}